// Round 2
// baseline (1187.496 us; speedup 1.0000x reference)
//
#include <hip/hip_runtime.h>
#include <cstdint>

typedef short v8s __attribute__((ext_vector_type(8)));
typedef float v4f __attribute__((ext_vector_type(4)));

#define M_ROWS 11520
#define K1 512
#define N1 2048       // GEMM1 N padded from 1960 (16 tiles of 128)
#define C_REAL 1960
#define K2 1984       // GEMM2 K padded from 1960 (62 steps of 32)
#define N2 512

__device__ __forceinline__ ushort f2b(float f) {
  union { float f; unsigned u; } v; v.f = f;
  unsigned r = v.u + 0x7FFFu + ((v.u >> 16) & 1u);   // RNE; inputs finite
  return (ushort)(r >> 16);
}

__global__ void cast_x(const float* __restrict__ x, ushort* __restrict__ xb) {
  int i = blockIdx.x * 256 + threadIdx.x;
  if (i < M_ROWS * K1) xb[i] = f2b(x[i]);
}

__global__ void cast_w1(const float* __restrict__ w1, ushort* __restrict__ w1b) {
  int i = blockIdx.x * 256 + threadIdx.x;   // over 512*2048
  if (i >= K1 * N1) return;
  int k = i >> 11, n = i & (N1 - 1);
  w1b[i] = (n < C_REAL) ? f2b(w1[k * C_REAL + n]) : (ushort)0;
}

__global__ void cast_w2(const float* __restrict__ w2, ushort* __restrict__ w2b) {
  int i = blockIdx.x * 256 + threadIdx.x;   // over 1984*512
  if (i >= K2 * N2) return;
  int k = i >> 9;
  w2b[i] = (k < C_REAL) ? f2b(w2[i]) : (ushort)0;
}

// ---------------- bf16 MFMA GEMM: C(MxN fp32) = A(MxK bf16) @ B(KxN bf16) + bias
// Block 256 thr = 4 waves, tile 128x128, BK=32. Wave w -> 64x64 quadrant,
// 4x4 grid of 16x16x32 MFMA. Fragment layouts per verified gfx950 mapping:
//   a[j] = A[m=lane&15][k=(lane>>4)*8+j], b[j] = B[k][n=lane&15],
//   d[r] = D[row=(lane>>4)*4+r][col=lane&15].
__global__ __launch_bounds__(256) void gemm_bf16(
    const ushort* __restrict__ A, const ushort* __restrict__ B,
    const float* __restrict__ bias, int nb,
    float* __restrict__ C, int N, int K)
{
  __shared__ ushort As[128][32];
  __shared__ ushort Bs[128][32];
  const int tid = threadIdx.x;
  const int bm = blockIdx.y * 128;
  const int bn = blockIdx.x * 128;
  const int wave = tid >> 6, lane = tid & 63;
  const int quad = lane >> 4, l16 = lane & 15;
  const int wm = (wave >> 1) * 64, wn = (wave & 1) * 64;

  v4f acc[4][4];
  #pragma unroll
  for (int i = 0; i < 4; ++i)
    #pragma unroll
    for (int j = 0; j < 4; ++j) acc[i][j] = (v4f){0.f, 0.f, 0.f, 0.f};

  const int am = tid >> 2, ak = (tid & 3) * 8;      // A stage: 2 rows/thread
  const int bk = tid >> 4, bn8 = (tid & 15) * 8;    // B stage: 2 k-rows/thread

  for (int k0 = 0; k0 < K; k0 += 32) {
    int4 va0 = *(const int4*)(A + (size_t)(bm + am) * K + k0 + ak);
    int4 va1 = *(const int4*)(A + (size_t)(bm + am + 64) * K + k0 + ak);
    int4 vb0 = *(const int4*)(B + (size_t)(k0 + bk) * N + bn + bn8);
    int4 vb1 = *(const int4*)(B + (size_t)(k0 + bk + 16) * N + bn + bn8);
    __syncthreads();
    *(int4*)&As[am][ak] = va0;
    *(int4*)&As[am + 64][ak] = va1;
    const ushort* p0 = (const ushort*)&vb0;
    const ushort* p1 = (const ushort*)&vb1;
    #pragma unroll
    for (int j = 0; j < 8; ++j) Bs[bn8 + j][bk] = p0[j];
    #pragma unroll
    for (int j = 0; j < 8; ++j) Bs[bn8 + j][bk + 16] = p1[j];
    __syncthreads();

    v8s af[4], bf[4];
    #pragma unroll
    for (int i = 0; i < 4; ++i) af[i] = *(const v8s*)&As[wm + i * 16 + l16][quad * 8];
    #pragma unroll
    for (int j = 0; j < 4; ++j) bf[j] = *(const v8s*)&Bs[wn + j * 16 + l16][quad * 8];
    #pragma unroll
    for (int i = 0; i < 4; ++i)
      #pragma unroll
      for (int j = 0; j < 4; ++j)
        acc[i][j] = __builtin_amdgcn_mfma_f32_16x16x32_bf16(af[i], bf[j], acc[i][j], 0, 0, 0);
  }

  #pragma unroll
  for (int i = 0; i < 4; ++i) {
    #pragma unroll
    for (int j = 0; j < 4; ++j) {
      int col = bn + wn + j * 16 + l16;
      float bv = (col < nb) ? bias[col] : 0.f;
      #pragma unroll
      for (int r = 0; r < 4; ++r) {
        int row = bm + wm + i * 16 + quad * 4 + r;
        C[(size_t)row * N + col] = acc[i][j][r] + bv;
      }
    }
  }
}

// ---------------- fold -> /norm -> unfold, in place on A (11520 x 2048, fp32).
// One block per (bt, ch) plane; scatter-add into padded 66x114 grid in LDS,
// then gather back with coverage-count division (0 outside interior).
__global__ __launch_bounds__(256) void fold_unfold(float* __restrict__ A) {
  __shared__ float S[66 * 114];
  const int plane = blockIdx.x;          // 0..639
  const int bt = plane / 40, ch = plane % 40;
  const int tid = threadIdx.x;
  for (int i = tid; i < 66 * 114; i += 256) S[i] = 0.f;
  __syncthreads();
  const size_t base = (size_t)bt * 720 * N1 + ch * 49;
  for (int idx = tid; idx < 720 * 49; idx += 256) {
    int v = idx / 49, t = idx - v * 49;
    int ho = v / 36, wo = v - ho * 36;
    int ki = t / 7, kj = t - ki * 7;
    float val = A[base + (size_t)v * N1 + t];
    atomicAdd(&S[(ho * 3 + ki) * 114 + (wo * 3 + kj)], val);
  }
  __syncthreads();
  for (int idx = tid; idx < 720 * 49; idx += 256) {
    int v = idx / 49, t = idx - v * 49;
    int ho = v / 36, wo = v - ho * 36;
    int ki = t / 7, kj = t - ki * 7;
    int py = ho * 3 + ki, px = wo * 3 + kj;
    float out = 0.f;
    if (py >= 3 && py < 63 && px >= 3 && px < 111) {
      int ry = py % 3, cy = 0;
      #pragma unroll
      for (int k = 0; k < 3; ++k) {
        int ki2 = ry + 3 * k;
        if (ki2 < 7) { int hh = (py - ki2) / 3; if (py - ki2 >= 0 && hh < 20) cy++; }
      }
      int rx = px % 3, cx = 0;
      #pragma unroll
      for (int k = 0; k < 3; ++k) {
        int kj2 = rx + 3 * k;
        if (kj2 < 7) { int wwv = (px - kj2) / 3; if (px - kj2 >= 0 && wwv < 36) cx++; }
      }
      out = S[py * 114 + px] / (float)(cy * cx);
    }
    A[base + (size_t)v * N1 + t] = out;
  }
}

// ---------------- depthwise conv (3x3 pad1 for ch<980, 5x5 pad2 for ch>=980)
// + exact GELU, emit bf16 G (11520 x 1984, K-pad cols zeroed).
__global__ __launch_bounds__(256) void dwconv_gelu(const float* __restrict__ A,
    const float* __restrict__ w3, const float* __restrict__ b3,
    const float* __restrict__ w5, const float* __restrict__ b5,
    ushort* __restrict__ G)
{
  int col = blockIdx.x * 256 + threadIdx.x;
  if (col >= K2) return;
  int r = blockIdx.y;                     // 0..11519
  if (col >= C_REAL) { G[(size_t)r * K2 + col] = 0; return; }
  int bt = r / 720, v = r - bt * 720;
  int h = v / 36, w = v - h * 36;
  const float* base = A + (size_t)bt * 720 * N1 + col;
  float y;
  if (col < 980) {
    y = b3[col];
    #pragma unroll
    for (int dy = 0; dy < 3; ++dy) {
      int hh = h + dy - 1; if (hh < 0 || hh >= 20) continue;
      #pragma unroll
      for (int dx = 0; dx < 3; ++dx) {
        int ww = w + dx - 1; if (ww < 0 || ww >= 36) continue;
        y += w3[col * 9 + dy * 3 + dx] * base[(size_t)(hh * 36 + ww) * N1];
      }
    }
  } else {
    int c5 = col - 980;
    y = b5[c5];
    #pragma unroll
    for (int dy = 0; dy < 5; ++dy) {
      int hh = h + dy - 2; if (hh < 0 || hh >= 20) continue;
      #pragma unroll
      for (int dx = 0; dx < 5; ++dx) {
        int ww = w + dx - 2; if (ww < 0 || ww >= 36) continue;
        y += w5[c5 * 25 + dy * 5 + dx] * base[(size_t)(hh * 36 + ww) * N1];
      }
    }
  }
  float g = 0.5f * y * (1.0f + erff(y * 0.70710678118654752f));
  G[(size_t)r * K2 + col] = f2b(g);
}

extern "C" void kernel_launch(void* const* d_in, const int* in_sizes, int n_in,
                              void* d_out, int out_size, void* d_ws, size_t ws_size,
                              hipStream_t stream) {
  const float* x  = (const float*)d_in[0];
  const float* w1 = (const float*)d_in[1];
  const float* b1 = (const float*)d_in[2];
  const float* w3 = (const float*)d_in[3];
  const float* b3 = (const float*)d_in[4];
  const float* w5 = (const float*)d_in[5];
  const float* b5 = (const float*)d_in[6];
  const float* w2 = (const float*)d_in[7];
  const float* b2 = (const float*)d_in[8];
  float* out = (float*)d_out;

  char* ws = (char*)d_ws;
  ushort* Xb  = (ushort*)(ws);               // 11520*512  bf16  = 11,796,480 B
  ushort* W1b = (ushort*)(ws + 11796480);    // 512*2048   bf16  =  2,097,152 B
  ushort* W2b = (ushort*)(ws + 13893632);    // 1984*512   bf16  =  2,031,616 B
  float*  Aw  = (float*)(ws + 15925248);     // 11520*2048 fp32  = 94,371,840 B
  ushort* G   = (ushort*)(ws + 110297088);   // 11520*1984 bf16  = 45,711,360 B
                                             // total 156,008,448 B

  hipLaunchKernelGGL(cast_x,  dim3((M_ROWS * K1) / 256), dim3(256), 0, stream, x, Xb);
  hipLaunchKernelGGL(cast_w1, dim3((K1 * N1) / 256),     dim3(256), 0, stream, w1, W1b);
  hipLaunchKernelGGL(cast_w2, dim3((K2 * N2) / 256),     dim3(256), 0, stream, w2, W2b);
  hipLaunchKernelGGL(gemm_bf16, dim3(N1 / 128, M_ROWS / 128), dim3(256), 0, stream,
                     Xb, W1b, b1, C_REAL, Aw, N1, K1);
  hipLaunchKernelGGL(fold_unfold, dim3(640), dim3(256), 0, stream, Aw);
  hipLaunchKernelGGL(dwconv_gelu, dim3((K2 + 255) / 256, M_ROWS), dim3(256), 0, stream,
                     Aw, w3, b3, w5, b5, G);
  hipLaunchKernelGGL(gemm_bf16, dim3(N2 / 128, M_ROWS / 128), dim3(256), 0, stream,
                     G, W2b, b2, N2, out, N2, K2);
}

// Round 3
// 562.268 us; speedup vs baseline: 2.1120x; 2.1120x over previous
//
#include <hip/hip_runtime.h>
#include <cstdint>

typedef short v8s __attribute__((ext_vector_type(8)));
typedef float v4f __attribute__((ext_vector_type(4)));

#define M_ROWS 11520
#define K1 512
#define N1 2048       // GEMM1 N padded from 1960 (16 tiles of 128)
#define C_REAL 1960
#define K2 1984       // GEMM2 K padded from 1960 (62 steps of 32)
#define N2 512

__device__ __forceinline__ ushort f2b(float f) {
  union { float f; unsigned u; } v; v.f = f;
  unsigned r = v.u + 0x7FFFu + ((v.u >> 16) & 1u);   // RNE; inputs finite
  return (ushort)(r >> 16);
}

__global__ void cast_x(const float* __restrict__ x, ushort* __restrict__ xb) {
  int i = blockIdx.x * 256 + threadIdx.x;
  if (i < M_ROWS * K1) xb[i] = f2b(x[i]);
}

__global__ void cast_w1(const float* __restrict__ w1, ushort* __restrict__ w1b) {
  int i = blockIdx.x * 256 + threadIdx.x;   // over 512*2048
  if (i >= K1 * N1) return;
  int k = i >> 11, n = i & (N1 - 1);
  w1b[i] = (n < C_REAL) ? f2b(w1[k * C_REAL + n]) : (ushort)0;
}

__global__ void cast_w2(const float* __restrict__ w2, ushort* __restrict__ w2b) {
  int i = blockIdx.x * 256 + threadIdx.x;   // over 1984*512
  if (i >= K2 * N2) return;
  int k = i >> 9;
  w2b[i] = (k < C_REAL) ? f2b(w2[i]) : (ushort)0;
}

__global__ void zero_gpad(ushort* __restrict__ G) {
  int i = blockIdx.x * 256 + threadIdx.x;   // over 11520*24
  if (i >= M_ROWS * (K2 - C_REAL)) return;
  int r = i / 24, j = i - r * 24;
  G[(size_t)r * K2 + C_REAL + j] = 0;
}

// ---------------- bf16 MFMA GEMM: C(MxN fp32) = A(MxK bf16) @ B(KxN bf16) + bias
__global__ __launch_bounds__(256) void gemm_bf16(
    const ushort* __restrict__ A, const ushort* __restrict__ B,
    const float* __restrict__ bias, int nb,
    float* __restrict__ C, int N, int K)
{
  __shared__ ushort As[128][32];
  __shared__ ushort Bs[128][32];
  const int tid = threadIdx.x;
  const int bm = blockIdx.y * 128;
  const int bn = blockIdx.x * 128;
  const int wave = tid >> 6, lane = tid & 63;
  const int quad = lane >> 4, l16 = lane & 15;
  const int wm = (wave >> 1) * 64, wn = (wave & 1) * 64;

  v4f acc[4][4];
  #pragma unroll
  for (int i = 0; i < 4; ++i)
    #pragma unroll
    for (int j = 0; j < 4; ++j) acc[i][j] = (v4f){0.f, 0.f, 0.f, 0.f};

  const int am = tid >> 2, ak = (tid & 3) * 8;      // A stage: 2 rows/thread
  const int bk = tid >> 4, bn8 = (tid & 15) * 8;    // B stage: 2 k-rows/thread

  for (int k0 = 0; k0 < K; k0 += 32) {
    int4 va0 = *(const int4*)(A + (size_t)(bm + am) * K + k0 + ak);
    int4 va1 = *(const int4*)(A + (size_t)(bm + am + 64) * K + k0 + ak);
    int4 vb0 = *(const int4*)(B + (size_t)(k0 + bk) * N + bn + bn8);
    int4 vb1 = *(const int4*)(B + (size_t)(k0 + bk + 16) * N + bn + bn8);
    __syncthreads();
    *(int4*)&As[am][ak] = va0;
    *(int4*)&As[am + 64][ak] = va1;
    const ushort* p0 = (const ushort*)&vb0;
    const ushort* p1 = (const ushort*)&vb1;
    #pragma unroll
    for (int j = 0; j < 8; ++j) Bs[bn8 + j][bk] = p0[j];
    #pragma unroll
    for (int j = 0; j < 8; ++j) Bs[bn8 + j][bk + 16] = p1[j];
    __syncthreads();

    v8s af[4], bf[4];
    #pragma unroll
    for (int i = 0; i < 4; ++i) af[i] = *(const v8s*)&As[wm + i * 16 + l16][quad * 8];
    #pragma unroll
    for (int j = 0; j < 4; ++j) bf[j] = *(const v8s*)&Bs[wn + j * 16 + l16][quad * 8];
    #pragma unroll
    for (int i = 0; i < 4; ++i)
      #pragma unroll
      for (int j = 0; j < 4; ++j)
        acc[i][j] = __builtin_amdgcn_mfma_f32_16x16x32_bf16(af[i], bf[j], acc[i][j], 0, 0, 0);
  }

  #pragma unroll
  for (int i = 0; i < 4; ++i) {
    #pragma unroll
    for (int j = 0; j < 4; ++j) {
      int col = bn + wn + j * 16 + l16;
      float bv = (col < nb) ? bias[col] : 0.f;
      #pragma unroll
      for (int r = 0; r < 4; ++r) {
        int row = bm + wm + i * 16 + quad * 4 + r;
        C[(size_t)row * N + col] = acc[i][j][r] + bv;
      }
    }
  }
}

// ---------------- fused fold -> /norm -> unfold -> dwconv -> GELU -> bf16
// One block per (bt, ch) with ch in [0,40). The unfolded activation at
// (h', w', col=ch*49+ki*7+kj) equals Snorm[h'*3+ki][w'*3+kj], so the dwconv
// reads come straight from the 66x114 LDS plane — nothing is materialized.
template<int KS>
__device__ __forceinline__ void conv_from_S(const float* __restrict__ S,
    const float* __restrict__ Wl, const float* __restrict__ Bl,
    ushort* __restrict__ G, int bt, int colbase, int tid)
{
  constexpr int P = KS / 2;
  for (int idx = tid; idx < 36 * 49; idx += 256) {
    int wo = idx / 49, t = idx - wo * 49;
    int ki = t / 7, kj = t - ki * 7;
    float wgt[KS * KS];
    #pragma unroll
    for (int j = 0; j < KS * KS; ++j) wgt[j] = Wl[t * KS * KS + j];
    const float bias = Bl[t];
    int sx[KS]; bool vx[KS];
    #pragma unroll
    for (int dx = 0; dx < KS; ++dx) {
      int wq = wo + dx - P;
      vx[dx] = (wq >= 0 && wq < 36);
      sx[dx] = wq * 3 + kj;
    }
    float win[KS][KS];
    #pragma unroll
    for (int dy = 0; dy < KS; ++dy) {
      int hq = dy - P;   // row for h=0
      #pragma unroll
      for (int dx = 0; dx < KS; ++dx)
        win[dy][dx] = (hq >= 0 && hq < 20 && vx[dx]) ? S[(hq * 3 + ki) * 114 + sx[dx]] : 0.f;
    }
    ushort* gp = G + (size_t)(bt * 720 + wo) * K2 + colbase + t;
    for (int h = 0; h < 20; ++h) {
      float y = bias;
      #pragma unroll
      for (int dy = 0; dy < KS; ++dy)
        #pragma unroll
        for (int dx = 0; dx < KS; ++dx)
          y += wgt[dy * KS + dx] * win[dy][dx];
      float g = 0.5f * y * (1.0f + erff(y * 0.70710678118654752f));
      gp[(size_t)h * 36 * K2] = f2b(g);
      // shift window up, load row h' = h+1+P
      #pragma unroll
      for (int dy = 0; dy < KS - 1; ++dy)
        #pragma unroll
        for (int dx = 0; dx < KS; ++dx) win[dy][dx] = win[dy + 1][dx];
      int hq = h + 1 + P;
      #pragma unroll
      for (int dx = 0; dx < KS; ++dx)
        win[KS - 1][dx] = (hq < 20 && vx[dx]) ? S[(hq * 3 + ki) * 114 + sx[dx]] : 0.f;
    }
  }
}

__global__ __launch_bounds__(256) void fold_dwconv_gelu(
    const float* __restrict__ A,
    const float* __restrict__ w3, const float* __restrict__ b3,
    const float* __restrict__ w5, const float* __restrict__ b5,
    ushort* __restrict__ G)
{
  __shared__ float S[66 * 114];      // 30,096 B
  __shared__ float Wl[49 * 25];      //  4,900 B
  __shared__ float Bl[49];
  const int plane = blockIdx.x;      // 0..639
  const int bt = plane / 40, ch = plane % 40;
  const int tid = threadIdx.x;
  const int colbase = ch * 49;
  const bool is3 = (ch < 20);

  for (int i = tid; i < 66 * 114; i += 256) S[i] = 0.f;
  if (is3) {
    for (int i = tid; i < 49 * 9; i += 256) Wl[i] = w3[colbase * 9 + i];
    if (tid < 49) Bl[tid] = b3[colbase + tid];
  } else {
    int c5 = colbase - 980;
    for (int i = tid; i < 49 * 25; i += 256) Wl[i] = w5[c5 * 25 + i];
    if (tid < 49) Bl[tid] = b5[c5 + tid];
  }
  __syncthreads();

  // fold: scatter-add the (720 x 49) GEMM1 slice into the padded 66x114 plane
  const size_t abase = (size_t)bt * 720 * N1 + colbase;
  for (int idx = tid; idx < 720 * 49; idx += 256) {
    int v = idx / 49, t = idx - v * 49;
    int ho = v / 36, wo = v - ho * 36;
    int ki = t / 7, kj = t - ki * 7;
    atomicAdd(&S[(ho * 3 + ki) * 114 + (wo * 3 + kj)], A[abase + (size_t)v * N1 + t]);
  }
  __syncthreads();

  // normalize in place: interior / coverage-count, exterior -> 0
  for (int i = tid; i < 66 * 114; i += 256) {
    int py = i / 114, px = i - py * 114;
    float out = 0.f;
    if (py >= 3 && py < 63 && px >= 3 && px < 111) {
      int ry = py % 3, cy = 0;
      #pragma unroll
      for (int k = 0; k < 3; ++k) {
        int ki2 = ry + 3 * k;
        if (ki2 < 7) { int hh = (py - ki2) / 3; if (py - ki2 >= 0 && hh < 20) cy++; }
      }
      int rx = px % 3, cx = 0;
      #pragma unroll
      for (int k = 0; k < 3; ++k) {
        int kj2 = rx + 3 * k;
        if (kj2 < 7) { int wwv = (px - kj2) / 3; if (px - kj2 >= 0 && wwv < 36) cx++; }
      }
      out = S[i] / (float)(cy * cx);
    }
    S[i] = out;
  }
  __syncthreads();

  if (is3) conv_from_S<3>(S, Wl, Bl, G, bt, colbase, tid);
  else     conv_from_S<5>(S, Wl, Bl, G, bt, colbase, tid);
}

extern "C" void kernel_launch(void* const* d_in, const int* in_sizes, int n_in,
                              void* d_out, int out_size, void* d_ws, size_t ws_size,
                              hipStream_t stream) {
  const float* x  = (const float*)d_in[0];
  const float* w1 = (const float*)d_in[1];
  const float* b1 = (const float*)d_in[2];
  const float* w3 = (const float*)d_in[3];
  const float* b3 = (const float*)d_in[4];
  const float* w5 = (const float*)d_in[5];
  const float* b5 = (const float*)d_in[6];
  const float* w2 = (const float*)d_in[7];
  const float* b2 = (const float*)d_in[8];
  float* out = (float*)d_out;

  char* ws = (char*)d_ws;
  ushort* Xb  = (ushort*)(ws);               // 11520*512  bf16
  ushort* W1b = (ushort*)(ws + 11796480);    // 512*2048   bf16
  ushort* W2b = (ushort*)(ws + 13893632);    // 1984*512   bf16
  float*  Aw  = (float*)(ws + 15925248);     // 11520*2048 fp32
  ushort* G   = (ushort*)(ws + 110297088);   // 11520*1984 bf16

  hipLaunchKernelGGL(cast_x,  dim3((M_ROWS * K1) / 256), dim3(256), 0, stream, x, Xb);
  hipLaunchKernelGGL(cast_w1, dim3((K1 * N1) / 256),     dim3(256), 0, stream, w1, W1b);
  hipLaunchKernelGGL(cast_w2, dim3((K2 * N2) / 256),     dim3(256), 0, stream, w2, W2b);
  hipLaunchKernelGGL(zero_gpad, dim3((M_ROWS * 24 + 255) / 256), dim3(256), 0, stream, G);
  hipLaunchKernelGGL(gemm_bf16, dim3(N1 / 128, M_ROWS / 128), dim3(256), 0, stream,
                     Xb, W1b, b1, C_REAL, Aw, N1, K1);
  hipLaunchKernelGGL(fold_dwconv_gelu, dim3(640), dim3(256), 0, stream,
                     Aw, w3, b3, w5, b5, G);
  hipLaunchKernelGGL(gemm_bf16, dim3(N2 / 128, M_ROWS / 128), dim3(256), 0, stream,
                     G, W2b, b2, N2, out, N2, K2);
}

// Round 4
// 398.880 us; speedup vs baseline: 2.9771x; 1.4096x over previous
//
#include <hip/hip_runtime.h>
#include <cstdint>

typedef short v8s __attribute__((ext_vector_type(8)));
typedef float v4f __attribute__((ext_vector_type(4)));
typedef unsigned short u16;

#define M_ROWS 11520
#define K1 512
#define N1 2048       // GEMM1 N padded from 1960
#define C_REAL 1960
#define K2 1984       // GEMM2 K padded from 1960
#define N2 512

__device__ __forceinline__ u16 f2b(float f) {
  union { float f; unsigned u; } v; v.f = f;
  unsigned r = v.u + 0x7FFFu + ((v.u >> 16) & 1u);   // RNE; inputs finite
  return (u16)(r >> 16);
}
__device__ __forceinline__ float b2f(u16 b) {
  union { unsigned u; float f; } v; v.u = ((unsigned)b) << 16; return v.f;
}

// async global->LDS, 16B per lane, deposited at wave-uniform base + lane*16
__device__ __forceinline__ void gl2lds16(const u16* g, u16* l) {
  __builtin_amdgcn_global_load_lds(
      (const __attribute__((address_space(1))) unsigned int*)g,
      (__attribute__((address_space(3))) unsigned int*)l, 16, 0, 0);
}

__global__ void cast_x8(const float* __restrict__ x, u16* __restrict__ xb) {
  int i = blockIdx.x * 256 + threadIdx.x;          // 737280 threads, 8 elems each
  const float4 a = ((const float4*)x)[2 * i];
  const float4 b = ((const float4*)x)[2 * i + 1];
  u16 o[8] = {f2b(a.x), f2b(a.y), f2b(a.z), f2b(a.w),
              f2b(b.x), f2b(b.y), f2b(b.z), f2b(b.w)};
  ((int4*)xb)[i] = *(const int4*)o;
}

// dst[n][k] = (k < R && n < C) ? src[k*C + n] : 0   (bf16 out, LDS 32x33 tiles)
__global__ __launch_bounds__(256) void transpose_cast(
    const float* __restrict__ src, u16* __restrict__ dst, int R, int C, int KP)
{
  __shared__ float T[32][33];
  const int n0 = blockIdx.x * 32, k0 = blockIdx.y * 32;
  const int tx = threadIdx.x & 31, ty = threadIdx.x >> 5;
  #pragma unroll
  for (int r = 0; r < 4; ++r) {
    int k = k0 + ty + 8 * r, n = n0 + tx;
    T[ty + 8 * r][tx] = (k < R && n < C) ? src[(size_t)k * C + n] : 0.f;
  }
  __syncthreads();
  #pragma unroll
  for (int r = 0; r < 4; ++r) {
    int n = n0 + ty + 8 * r, k = k0 + tx;
    if (k < KP) dst[(size_t)n * KP + k] = f2b(T[tx][ty + 8 * r]);
  }
}

__global__ void zero_gpad(u16* __restrict__ G) {
  int i = blockIdx.x * 256 + threadIdx.x;   // 11520*24
  int r = i / 24, j = i - r * 24;
  G[(size_t)r * K2 + C_REAL + j] = 0;
}

__device__ __forceinline__ void stv(float v, float* p) { *p = v; }
__device__ __forceinline__ void stv(float v, u16* p) { *p = f2b(v); }

// ------- m97-style bf16 MFMA GEMM: C = A(MxK) @ BT(NxK)^T + bias
// 128x128 tile, BK=32, global_load_lds width-16 staging for both operands.
template<typename OT>
__global__ __launch_bounds__(256) void gemm_bt(
    const u16* __restrict__ A, const u16* __restrict__ BT,
    const float* __restrict__ bias, int nb, OT* __restrict__ C, int N, int K)
{
  __shared__ u16 As[128 * 32];
  __shared__ u16 Bs[128 * 32];
  const int tid = threadIdx.x;
  const int bm = blockIdx.y * 128, bn = blockIdx.x * 128;
  const int wave = tid >> 6, lane = tid & 63;
  const int quad = lane >> 4, l16 = lane & 15;
  const int wm = (wave >> 1) * 64, wn = (wave & 1) * 64;
  const int sr = lane >> 2, sc = (lane & 3) * 8;   // staging: 16 rows x 32 cols per issue

  const u16* pA0 = A + (size_t)(bm + wave * 32 + sr) * K + sc;
  const u16* pA1 = pA0 + (size_t)16 * K;
  const u16* pB0 = BT + (size_t)(bn + wave * 32 + sr) * K + sc;
  const u16* pB1 = pB0 + (size_t)16 * K;
  u16* lA0 = As + (wave * 32) * 32;
  u16* lA1 = As + (wave * 32 + 16) * 32;
  u16* lB0 = Bs + (wave * 32) * 32;
  u16* lB1 = Bs + (wave * 32 + 16) * 32;

  v4f acc[4][4];
  #pragma unroll
  for (int i = 0; i < 4; ++i)
    #pragma unroll
    for (int j = 0; j < 4; ++j) acc[i][j] = (v4f){0.f, 0.f, 0.f, 0.f};

  for (int k0 = 0; k0 < K; k0 += 32) {
    gl2lds16(pA0, lA0); gl2lds16(pA1, lA1);
    gl2lds16(pB0, lB0); gl2lds16(pB1, lB1);
    pA0 += 32; pA1 += 32; pB0 += 32; pB1 += 32;
    __syncthreads();                     // drains vmcnt: staging visible
    v8s af[4], bf[4];
    #pragma unroll
    for (int i = 0; i < 4; ++i) af[i] = *(const v8s*)&As[(wm + i * 16 + l16) * 32 + quad * 8];
    #pragma unroll
    for (int j = 0; j < 4; ++j) bf[j] = *(const v8s*)&Bs[(wn + j * 16 + l16) * 32 + quad * 8];
    #pragma unroll
    for (int i = 0; i < 4; ++i)
      #pragma unroll
      for (int j = 0; j < 4; ++j)
        acc[i][j] = __builtin_amdgcn_mfma_f32_16x16x32_bf16(af[i], bf[j], acc[i][j], 0, 0, 0);
    __syncthreads();                     // compute done before next overwrite
  }

  #pragma unroll
  for (int i = 0; i < 4; ++i) {
    #pragma unroll
    for (int j = 0; j < 4; ++j) {
      int col = bn + wn + j * 16 + l16;
      float bv = (col < nb) ? bias[col] : 0.f;
      #pragma unroll
      for (int r = 0; r < 4; ++r) {
        int row = bm + wm + i * 16 + quad * 4 + r;
        stv(acc[i][j][r] + bv, C + (size_t)row * N + col);
      }
    }
  }
}

// ------- fold + normalize: Aw(bf16 slice 720x49) -> Snorm plane (66x114 fp32)
__global__ __launch_bounds__(256) void fold_norm(const u16* __restrict__ A,
                                                 float* __restrict__ Sn)
{
  __shared__ float S[66 * 114];
  const int plane = blockIdx.x, bt = plane / 40, ch = plane % 40;
  const int tid = threadIdx.x;
  for (int i = tid; i < 66 * 114; i += 256) S[i] = 0.f;
  __syncthreads();
  const size_t abase = (size_t)bt * 720 * N1 + ch * 49;
  for (int idx = tid; idx < 720 * 49; idx += 256) {
    int v = idx / 49, t = idx - v * 49;
    int ho = v / 36, wo = v - ho * 36;
    int ki = t / 7, kj = t - ki * 7;
    atomicAdd(&S[(ho * 3 + ki) * 114 + (wo * 3 + kj)], b2f(A[abase + (size_t)v * N1 + t]));
  }
  __syncthreads();
  float* out = Sn + (size_t)plane * 7524;
  for (int i = tid; i < 66 * 114; i += 256) {
    int py = i / 114, px = i - py * 114;
    float val = 0.f;
    if (py >= 3 && py < 63 && px >= 3 && px < 111) {
      int ry = py % 3, cy = 0;
      #pragma unroll
      for (int k = 0; k < 3; ++k) {
        int ki2 = ry + 3 * k;
        if (ki2 < 7) { int hh = (py - ki2) / 3; if (py - ki2 >= 0 && hh < 20) cy++; }
      }
      int rx = px % 3, cx = 0;
      #pragma unroll
      for (int k = 0; k < 3; ++k) {
        int kj2 = rx + 3 * k;
        if (kj2 < 7) { int wwv = (px - kj2) / 3; if (px - kj2 >= 0 && wwv < 36) cx++; }
      }
      val = S[i] / (float)(cy * cx);
    }
    out[i] = val;
  }
}

// ------- dwconv + GELU from Snorm strips; grid (5, 640): 4 output rows/block
template<int KS>
__device__ __forceinline__ void conv_part(const float* __restrict__ Sl,
    const float* __restrict__ Wl, const float* __restrict__ Bl,
    u16* __restrict__ G, int bt, int colbase, int h0, int tid)
{
  constexpr int P = KS / 2;
  const int rbase = 3 * h0 - 6;          // Sl row 0 == Snorm row rbase
  for (int idx = tid; idx < 36 * 49; idx += 256) {
    int wo = idx / 49, t = idx - wo * 49;
    int ki = t / 7, kj = t - ki * 7;
    float wgt[KS * KS];
    #pragma unroll
    for (int j = 0; j < KS * KS; ++j) wgt[j] = Wl[t * KS * KS + j];
    const float bias = Bl[t];
    int sx[KS]; bool vx[KS];
    #pragma unroll
    for (int dx = 0; dx < KS; ++dx) {
      int wq = wo + dx - P;
      vx[dx] = (wq >= 0 && wq < 36);
      sx[dx] = wq * 3 + kj;
    }
    float win[KS][KS];
    #pragma unroll
    for (int dy = 0; dy < KS; ++dy) {
      int hq = h0 + dy - P;
      #pragma unroll
      for (int dx = 0; dx < KS; ++dx)
        win[dy][dx] = (hq >= 0 && hq < 20 && vx[dx])
                        ? Sl[(hq * 3 + ki - rbase) * 114 + sx[dx]] : 0.f;
    }
    u16* gp = G + (size_t)(bt * 720 + h0 * 36 + wo) * K2 + colbase + t;
    #pragma unroll
    for (int hh = 0; hh < 4; ++hh) {
      float y = bias;
      #pragma unroll
      for (int dy = 0; dy < KS; ++dy)
        #pragma unroll
        for (int dx = 0; dx < KS; ++dx)
          y += wgt[dy * KS + dx] * win[dy][dx];
      float g = 0.5f * y * (1.0f + erff(y * 0.70710678118654752f));
      *gp = f2b(g);
      gp += (size_t)36 * K2;
      if (hh < 3) {
        #pragma unroll
        for (int dy = 0; dy < KS - 1; ++dy)
          #pragma unroll
          for (int dx = 0; dx < KS; ++dx) win[dy][dx] = win[dy + 1][dx];
        int hq = h0 + hh + 1 + P;
        #pragma unroll
        for (int dx = 0; dx < KS; ++dx)
          win[KS - 1][dx] = (hq < 20 && vx[dx])
                              ? Sl[(hq * 3 + ki - rbase) * 114 + sx[dx]] : 0.f;
      }
    }
  }
}

__global__ __launch_bounds__(256) void dwconv_gelu2(const float* __restrict__ Sn,
    const float* __restrict__ w3, const float* __restrict__ b3,
    const float* __restrict__ w5, const float* __restrict__ b5,
    u16* __restrict__ G)
{
  __shared__ float Sl[28 * 114];     // Snorm rows [3h0-6, 3h0+21]
  __shared__ float Wl[49 * 25];
  __shared__ float Bl[49];
  const int plane = blockIdx.y, bt = plane / 40, ch = plane % 40;
  const int h0 = blockIdx.x * 4;
  const int tid = threadIdx.x;
  const int colbase = ch * 49;
  const bool is3 = (ch < 20);
  if (is3) {
    for (int i = tid; i < 49 * 9; i += 256) Wl[i] = w3[colbase * 9 + i];
    if (tid < 49) Bl[tid] = b3[colbase + tid];
  } else {
    int c5 = colbase - 980;
    for (int i = tid; i < 49 * 25; i += 256) Wl[i] = w5[c5 * 25 + i];
    if (tid < 49) Bl[tid] = b5[c5 + tid];
  }
  const int rbase = 3 * h0 - 6;
  const float* sp = Sn + (size_t)plane * 7524;
  for (int i = tid; i < 28 * 114; i += 256) {
    int r = i / 114, c = i - r * 114;
    int py = rbase + r;
    Sl[i] = (py >= 0 && py < 66) ? sp[py * 114 + c] : 0.f;
  }
  __syncthreads();
  if (is3) conv_part<3>(Sl, Wl, Bl, G, bt, colbase, h0, tid);
  else     conv_part<5>(Sl, Wl, Bl, G, bt, colbase, h0, tid);
}

extern "C" void kernel_launch(void* const* d_in, const int* in_sizes, int n_in,
                              void* d_out, int out_size, void* d_ws, size_t ws_size,
                              hipStream_t stream) {
  const float* x  = (const float*)d_in[0];
  const float* w1 = (const float*)d_in[1];
  const float* b1 = (const float*)d_in[2];
  const float* w3 = (const float*)d_in[3];
  const float* b3 = (const float*)d_in[4];
  const float* w5 = (const float*)d_in[5];
  const float* b5 = (const float*)d_in[6];
  const float* w2 = (const float*)d_in[7];
  const float* b2 = (const float*)d_in[8];
  float* out = (float*)d_out;

  char* ws = (char*)d_ws;
  u16*   Xb  = (u16*)(ws);                   // 11520*512  bf16 = 11,796,480
  u16*   W1T = (u16*)(ws + 11796480);        // 2048*512   bf16 =  2,097,152
  u16*   W2T = (u16*)(ws + 13893632);        // 512*1984   bf16 =  2,031,616
  u16*   Aw  = (u16*)(ws + 15925248);        // 11520*2048 bf16 = 47,185,920
  u16*   G   = (u16*)(ws + 63111168);        // 11520*1984 bf16 = 45,711,360
  float* Sn  = (float*)(ws + 108822528);     // 640*7524   fp32 = 19,261,440 -> 128,083,968 total

  hipLaunchKernelGGL(cast_x8, dim3(2880), dim3(256), 0, stream, x, Xb);
  hipLaunchKernelGGL(transpose_cast, dim3(64, 16), dim3(256), 0, stream, w1, W1T, K1, C_REAL, K1);
  hipLaunchKernelGGL(transpose_cast, dim3(16, 62), dim3(256), 0, stream, w2, W2T, C_REAL, N2, K2);
  hipLaunchKernelGGL(zero_gpad, dim3(1080), dim3(256), 0, stream, G);
  hipLaunchKernelGGL(gemm_bt<u16>, dim3(N1 / 128, M_ROWS / 128), dim3(256), 0, stream,
                     Xb, W1T, b1, C_REAL, Aw, N1, K1);
  hipLaunchKernelGGL(fold_norm, dim3(640), dim3(256), 0, stream, Aw, Sn);
  hipLaunchKernelGGL(dwconv_gelu2, dim3(5, 640), dim3(256), 0, stream,
                     Sn, w3, b3, w5, b5, G);
  hipLaunchKernelGGL(gemm_bt<float>, dim3(N2 / 128, M_ROWS / 128), dim3(256), 0, stream,
                     G, W2T, b2, N2, out, N2, K2);
}

// Round 5
// 330.455 us; speedup vs baseline: 3.5935x; 1.2071x over previous
//
#include <hip/hip_runtime.h>
#include <cstdint>

typedef short v8s __attribute__((ext_vector_type(8)));
typedef float v4f __attribute__((ext_vector_type(4)));
typedef unsigned short u16;

#define M_ROWS 11520
#define K1 512
#define N1 2048       // GEMM1 N padded from 1960
#define C_REAL 1960
#define K2 1984       // GEMM2 K padded from 1960
#define N2 512
#define TPAD 56       // fold-layout t padded 49 -> 56 (16B-aligned rows)
#define PLANE_ELEMS (720 * TPAD)   // 40320 elems = 80,640 B

__device__ __forceinline__ u16 f2b(float f) {
  union { float f; unsigned u; } v; v.f = f;
  unsigned r = v.u + 0x7FFFu + ((v.u >> 16) & 1u);   // RNE; inputs finite
  return (u16)(r >> 16);
}
__device__ __forceinline__ float b2f(u16 b) {
  union { unsigned u; float f; } v; v.u = ((unsigned)b) << 16; return v.f;
}

// async global->LDS, 16B per lane, deposited at wave-uniform base + lane*16
__device__ __forceinline__ void gl2lds16(const u16* g, u16* l) {
  __builtin_amdgcn_global_load_lds(
      (const __attribute__((address_space(1))) unsigned int*)g,
      (__attribute__((address_space(3))) unsigned int*)l, 16, 0, 0);
}

__global__ void cast_x8(const float* __restrict__ x, u16* __restrict__ xb) {
  int i = blockIdx.x * 256 + threadIdx.x;          // 737280 threads, 8 elems each
  const float4 a = ((const float4*)x)[2 * i];
  const float4 b = ((const float4*)x)[2 * i + 1];
  u16 o[8] = {f2b(a.x), f2b(a.y), f2b(a.z), f2b(a.w),
              f2b(b.x), f2b(b.y), f2b(b.z), f2b(b.w)};
  ((int4*)xb)[i] = *(const int4*)o;
}

// dst[n][k] = (k < R && n < C) ? src[k*C + n] : 0   (bf16 out, LDS 32x33 tiles)
__global__ __launch_bounds__(256) void transpose_cast(
    const float* __restrict__ src, u16* __restrict__ dst, int R, int C, int KP)
{
  __shared__ float T[32][33];
  const int n0 = blockIdx.x * 32, k0 = blockIdx.y * 32;
  const int tx = threadIdx.x & 31, ty = threadIdx.x >> 5;
  #pragma unroll
  for (int r = 0; r < 4; ++r) {
    int k = k0 + ty + 8 * r, n = n0 + tx;
    T[ty + 8 * r][tx] = (k < R && n < C) ? src[(size_t)k * C + n] : 0.f;
  }
  __syncthreads();
  #pragma unroll
  for (int r = 0; r < 4; ++r) {
    int n = n0 + ty + 8 * r, k = k0 + tx;
    if (k < KP) dst[(size_t)n * KP + k] = f2b(T[tx][ty + 8 * r]);
  }
}

__global__ void zero_gpad(u16* __restrict__ G) {
  int i = blockIdx.x * 256 + threadIdx.x;   // 11520*24
  int r = i / 24, j = i - r * 24;
  G[(size_t)r * K2 + C_REAL + j] = 0;
}

__device__ __forceinline__ void stv(float v, float* p) { *p = v; }
__device__ __forceinline__ void stv(float v, u16* p) { *p = f2b(v); }

// ------- m97-style bf16 MFMA GEMM: C = A(MxK) @ BT(NxK)^T + bias
// 128x128 tile, BK=32, global_load_lds width-16 staging for both operands.
// FOLD=true: emit bf16 into plane-major fold layout Aw[bt*40+ch][v][t] (t pad 56).
template<typename OT, bool FOLD>
__global__ __launch_bounds__(256) void gemm_bt(
    const u16* __restrict__ A, const u16* __restrict__ BT,
    const float* __restrict__ bias, int nb, OT* __restrict__ C, int N, int K)
{
  __shared__ u16 As[128 * 32];
  __shared__ u16 Bs[128 * 32];
  const int tid = threadIdx.x;
  const int bm = blockIdx.y * 128, bn = blockIdx.x * 128;
  const int wave = tid >> 6, lane = tid & 63;
  const int quad = lane >> 4, l16 = lane & 15;
  const int wm = (wave >> 1) * 64, wn = (wave & 1) * 64;
  const int sr = lane >> 2, sc = (lane & 3) * 8;   // staging: 16 rows x 32 cols per issue

  const u16* pA0 = A + (size_t)(bm + wave * 32 + sr) * K + sc;
  const u16* pA1 = pA0 + (size_t)16 * K;
  const u16* pB0 = BT + (size_t)(bn + wave * 32 + sr) * K + sc;
  const u16* pB1 = pB0 + (size_t)16 * K;
  u16* lA0 = As + (wave * 32) * 32;
  u16* lA1 = As + (wave * 32 + 16) * 32;
  u16* lB0 = Bs + (wave * 32) * 32;
  u16* lB1 = Bs + (wave * 32 + 16) * 32;

  v4f acc[4][4];
  #pragma unroll
  for (int i = 0; i < 4; ++i)
    #pragma unroll
    for (int j = 0; j < 4; ++j) acc[i][j] = (v4f){0.f, 0.f, 0.f, 0.f};

  for (int k0 = 0; k0 < K; k0 += 32) {
    gl2lds16(pA0, lA0); gl2lds16(pA1, lA1);
    gl2lds16(pB0, lB0); gl2lds16(pB1, lB1);
    pA0 += 32; pA1 += 32; pB0 += 32; pB1 += 32;
    __syncthreads();                     // drains vmcnt: staging visible
    v8s af[4], bf[4];
    #pragma unroll
    for (int i = 0; i < 4; ++i) af[i] = *(const v8s*)&As[(wm + i * 16 + l16) * 32 + quad * 8];
    #pragma unroll
    for (int j = 0; j < 4; ++j) bf[j] = *(const v8s*)&Bs[(wn + j * 16 + l16) * 32 + quad * 8];
    #pragma unroll
    for (int i = 0; i < 4; ++i)
      #pragma unroll
      for (int j = 0; j < 4; ++j)
        acc[i][j] = __builtin_amdgcn_mfma_f32_16x16x32_bf16(af[i], bf[j], acc[i][j], 0, 0, 0);
    __syncthreads();                     // compute done before next overwrite
  }

  #pragma unroll
  for (int i = 0; i < 4; ++i) {
    #pragma unroll
    for (int j = 0; j < 4; ++j) {
      int col = bn + wn + j * 16 + l16;
      if (FOLD && col >= C_REAL) continue;
      float bv = (col < nb) ? bias[col] : 0.f;
      int ch = 0, t = 0;
      if (FOLD) { ch = col / 49; t = col - ch * 49; }
      #pragma unroll
      for (int r = 0; r < 4; ++r) {
        int row = bm + wm + i * 16 + quad * 4 + r;
        float val = acc[i][j][r] + bv;
        if (FOLD) {
          int bt = row / 720, v = row - bt * 720;
          stv(val, C + (size_t)(bt * 40 + ch) * PLANE_ELEMS + v * TPAD + t);
        } else {
          stv(val, C + (size_t)row * N + col);
        }
      }
    }
  }
}

// ------- fold + normalize, gather formulation. One block per (bt,ch) plane.
// Stage the contiguous 720x56 bf16 slice into LDS (coalesced int4), then each
// Snorm cell gathers its <=9 contributors — no atomics.
__global__ __launch_bounds__(256) void fold_norm(const u16* __restrict__ Aw,
                                                 float* __restrict__ Sn)
{
  __shared__ u16 raw[PLANE_ELEMS];        // 80,640 B -> 2 blocks/CU
  const int plane = blockIdx.x;
  const int tid = threadIdx.x;
  const int4* src = (const int4*)(Aw + (size_t)plane * PLANE_ELEMS);
  int4* dst = (int4*)raw;
  for (int j = tid; j < PLANE_ELEMS / 8; j += 256) dst[j] = src[j];
  __syncthreads();

  float* out = Sn + (size_t)plane * 7524;
  for (int i = tid; i < 66 * 114; i += 256) {
    int py = i / 114, px = i - py * 114;
    float val = 0.f;
    if (py >= 3 && py < 63 && px >= 3 && px < 111) {
      int ry = py % 3, rx = px % 3;
      int hhs[3], kis[3], nki = 0;
      #pragma unroll
      for (int k = 0; k < 3; ++k) {
        int ki = ry + 3 * k;
        if (ki < 7 && py - ki >= 0) {
          int hh = (py - ki) / 3;
          if (hh < 20) { kis[nki] = ki; hhs[nki] = hh; ++nki; }
        }
      }
      int wws[3], kjs[3], nkj = 0;
      #pragma unroll
      for (int k = 0; k < 3; ++k) {
        int kj = rx + 3 * k;
        if (kj < 7 && px - kj >= 0) {
          int ww = (px - kj) / 3;
          if (ww < 36) { kjs[nkj] = kj; wws[nkj] = ww; ++nkj; }
        }
      }
      float sum = 0.f;
      for (int a = 0; a < nki; ++a) {
        int rowoff = (hhs[a] * 36) * TPAD + kis[a] * 7;
        for (int b = 0; b < nkj; ++b)
          sum += b2f(raw[rowoff + wws[b] * TPAD + kjs[b]]);
      }
      val = sum / (float)(nki * nkj);
    }
    out[i] = val;
  }
}

// ------- dwconv + GELU from Snorm strips; grid (5, 640): 4 output rows/block
template<int KS>
__device__ __forceinline__ void conv_part(const float* __restrict__ Sl,
    const float* __restrict__ Wl, const float* __restrict__ Bl,
    u16* __restrict__ G, int bt, int colbase, int h0, int tid)
{
  constexpr int P = KS / 2;
  const int rbase = 3 * h0 - 6;          // Sl row 0 == Snorm row rbase
  for (int idx = tid; idx < 36 * 49; idx += 256) {
    int wo = idx / 49, t = idx - wo * 49;
    int ki = t / 7, kj = t - ki * 7;
    float wgt[KS * KS];
    #pragma unroll
    for (int j = 0; j < KS * KS; ++j) wgt[j] = Wl[t * KS * KS + j];
    const float bias = Bl[t];
    int sx[KS]; bool vx[KS];
    #pragma unroll
    for (int dx = 0; dx < KS; ++dx) {
      int wq = wo + dx - P;
      vx[dx] = (wq >= 0 && wq < 36);
      sx[dx] = wq * 3 + kj;
    }
    float win[KS][KS];
    #pragma unroll
    for (int dy = 0; dy < KS; ++dy) {
      int hq = h0 + dy - P;
      #pragma unroll
      for (int dx = 0; dx < KS; ++dx)
        win[dy][dx] = (hq >= 0 && hq < 20 && vx[dx])
                        ? Sl[(hq * 3 + ki - rbase) * 114 + sx[dx]] : 0.f;
    }
    u16* gp = G + (size_t)(bt * 720 + h0 * 36 + wo) * K2 + colbase + t;
    #pragma unroll
    for (int hh = 0; hh < 4; ++hh) {
      float y = bias;
      #pragma unroll
      for (int dy = 0; dy < KS; ++dy)
        #pragma unroll
        for (int dx = 0; dx < KS; ++dx)
          y += wgt[dy * KS + dx] * win[dy][dx];
      float g = 0.5f * y * (1.0f + erff(y * 0.70710678118654752f));
      *gp = f2b(g);
      gp += (size_t)36 * K2;
      if (hh < 3) {
        #pragma unroll
        for (int dy = 0; dy < KS - 1; ++dy)
          #pragma unroll
          for (int dx = 0; dx < KS; ++dx) win[dy][dx] = win[dy + 1][dx];
        int hq = h0 + hh + 1 + P;
        #pragma unroll
        for (int dx = 0; dx < KS; ++dx)
          win[KS - 1][dx] = (hq < 20 && vx[dx])
                              ? Sl[(hq * 3 + ki - rbase) * 114 + sx[dx]] : 0.f;
      }
    }
  }
}

__global__ __launch_bounds__(256) void dwconv_gelu2(const float* __restrict__ Sn,
    const float* __restrict__ w3, const float* __restrict__ b3,
    const float* __restrict__ w5, const float* __restrict__ b5,
    u16* __restrict__ G)
{
  __shared__ float Sl[28 * 114];     // Snorm rows [3h0-6, 3h0+21]
  __shared__ float Wl[49 * 25];
  __shared__ float Bl[49];
  const int plane = blockIdx.y, bt = plane / 40, ch = plane % 40;
  const int h0 = blockIdx.x * 4;
  const int tid = threadIdx.x;
  const int colbase = ch * 49;
  const bool is3 = (ch < 20);
  if (is3) {
    for (int i = tid; i < 49 * 9; i += 256) Wl[i] = w3[colbase * 9 + i];
    if (tid < 49) Bl[tid] = b3[colbase + tid];
  } else {
    int c5 = colbase - 980;
    for (int i = tid; i < 49 * 25; i += 256) Wl[i] = w5[c5 * 25 + i];
    if (tid < 49) Bl[tid] = b5[c5 + tid];
  }
  const int rbase = 3 * h0 - 6;
  const float* sp = Sn + (size_t)plane * 7524;
  for (int i = tid; i < 28 * 114; i += 256) {
    int r = i / 114, c = i - r * 114;
    int py = rbase + r;
    Sl[i] = (py >= 0 && py < 66) ? sp[py * 114 + c] : 0.f;
  }
  __syncthreads();
  if (is3) conv_part<3>(Sl, Wl, Bl, G, bt, colbase, h0, tid);
  else     conv_part<5>(Sl, Wl, Bl, G, bt, colbase, h0, tid);
}

extern "C" void kernel_launch(void* const* d_in, const int* in_sizes, int n_in,
                              void* d_out, int out_size, void* d_ws, size_t ws_size,
                              hipStream_t stream) {
  const float* x  = (const float*)d_in[0];
  const float* w1 = (const float*)d_in[1];
  const float* b1 = (const float*)d_in[2];
  const float* w3 = (const float*)d_in[3];
  const float* b3 = (const float*)d_in[4];
  const float* w5 = (const float*)d_in[5];
  const float* b5 = (const float*)d_in[6];
  const float* w2 = (const float*)d_in[7];
  const float* b2 = (const float*)d_in[8];
  float* out = (float*)d_out;

  char* ws = (char*)d_ws;
  u16*   Xb  = (u16*)(ws);                   // 11520*512  bf16 = 11,796,480
  u16*   W1T = (u16*)(ws + 11796480);        // 2048*512   bf16 =  2,097,152
  u16*   W2T = (u16*)(ws + 13893632);        // 512*1984   bf16 =  2,031,616
  u16*   Aw  = (u16*)(ws + 15925248);        // 640*40320  bf16 = 51,609,600 (fold layout)
  u16*   G   = (u16*)(ws + 67534848);        // 11520*1984 bf16 = 45,711,360
  float* Sn  = (float*)(ws + 113246208);     // 640*7524   fp32 = 19,261,440 -> 132,507,648 total

  hipLaunchKernelGGL(cast_x8, dim3(2880), dim3(256), 0, stream, x, Xb);
  hipLaunchKernelGGL(transpose_cast, dim3(64, 16), dim3(256), 0, stream, w1, W1T, K1, C_REAL, K1);
  hipLaunchKernelGGL(transpose_cast, dim3(16, 62), dim3(256), 0, stream, w2, W2T, C_REAL, N2, K2);
  hipLaunchKernelGGL(zero_gpad, dim3(1080), dim3(256), 0, stream, G);
  hipLaunchKernelGGL((gemm_bt<u16, true>), dim3(N1 / 128, M_ROWS / 128), dim3(256), 0, stream,
                     Xb, W1T, b1, C_REAL, Aw, N1, K1);
  hipLaunchKernelGGL(fold_norm, dim3(640), dim3(256), 0, stream, Aw, Sn);
  hipLaunchKernelGGL(dwconv_gelu2, dim3(5, 640), dim3(256), 0, stream,
                     Sn, w3, b3, w5, b5, G);
  hipLaunchKernelGGL((gemm_bt<float, false>), dim3(N2 / 128, M_ROWS / 128), dim3(256), 0, stream,
                     G, W2T, b2, N2, out, N2, K2);
}